// Round 7
// baseline (154.048 us; speedup 1.0000x reference)
//
#include <hip/hip_runtime.h>
#include <hip/hip_bf16.h>

// GRUCell (B=262144, IN=2, H=50) + critic + actor-softmax.
// Inputs fp32, outputs fp32: d_out = h_new[B,50] | c[B,1] | pi[B,2].
// Extended-K MFMA: x[64]=[h(50),s(2),1,0...], W[64]=[w_hh,w_ih,bias,0...].
// R13: six variants (R7-R12) all pinned at 48-51us. The one structure all
// of them shared: the per-tile LDS round-trip (stage x -> fence -> ds_read
// A-frags + 16x ds_read_u16 hv) and LDS-resident weight fragments (which
// the allocator silently kept re-reading in R12, VGPR=108). R13 removes
// LDS from the kernel COMPLETELY:
//  - A-fragments: lane (c16,quad) needs h[row][quad*8..+7] = 8 consecutive
//    floats -> direct global float2 loads + cvt_pk packing. k>=48 boundary
//    (h48,h49,s0,s1,1.0,0...) patched per-quad.
//  - Weight B-fragments: 8 consecutive floats of a w_hh row per lane, same
//    boundary patch; loaded ONCE per wave into 24 bf16x8 regs (96 VGPR),
//    straight from global - no LDS copy for the allocator to fall back to.
//  - hv / srow: direct global loads (L1/L2-hot; same rows as A-loads).
// No __shared__, no barriers, no fences. The loop is pure: issue ~30
// independent VMEM loads -> pack -> 24 reg-MFMAs -> gate math -> DPP
// heads -> stores. Keeps R10 DPP reduction + R11 VALU trims.
// Activation signals: LDS_Block_Size=0, SQ_LDS_BANK_CONFLICT~0.

#define BDIM 256

typedef __bf16 bf16x8 __attribute__((ext_vector_type(8)));
typedef float f32x4 __attribute__((ext_vector_type(4)));

__device__ __forceinline__ unsigned packbf(float a, float b) {  // v_cvt_pk_bf16_f32
    union { __hip_bfloat162 h; unsigned u; } c;
    c.h = __float22bfloat162_rn(make_float2(a, b));
    return c.u;
}
__device__ __forceinline__ bf16x8 pack8(float2 a, float2 b, float2 c, float2 d) {
    union { unsigned u[4]; bf16x8 v; } r;
    r.u[0] = packbf(a.x, a.y); r.u[1] = packbf(b.x, b.y);
    r.u[2] = packbf(c.x, c.y); r.u[3] = packbf(d.x, d.y);
    return r.v;
}

// DPP rotate-add within each 16-lane row: VALU pipe, no LDS.
template <int CTRL>
__device__ __forceinline__ float dpp_add(float v) {
    int s = __builtin_bit_cast(int, v);
    int r = __builtin_amdgcn_update_dpp(s, s, CTRL, 0xf, 0xf, false);
    return v + __builtin_bit_cast(float, r);
}
__device__ __forceinline__ float row16_sum(float v) {
    v = dpp_add<0x128>(v);   // + ror 8
    v = dpp_add<0x124>(v);   // + ror 4
    v = dpp_add<0x122>(v);   // + ror 2
    v = dpp_add<0x121>(v);   // + ror 1 -> every lane has full 16-lane sum
    return v;
}

__global__ __launch_bounds__(BDIM, 2) void gru_fused(
    const float* __restrict__ s,
    const float* __restrict__ h,
    const float* __restrict__ w_ih,
    const float* __restrict__ w_hh,
    const float* __restrict__ b_ih,
    const float* __restrict__ b_hh,
    const float* __restrict__ actor_w,
    const float* __restrict__ actor_b,
    const float* __restrict__ critic_w,
    const float* __restrict__ critic_b,
    float* __restrict__ out,
    int Btot, int nTiles)
{
    const int tid  = threadIdx.x;
    const int wave = tid >> 6;           // 0..3
    const int lane = tid & 63;
    const int c16  = lane & 15;
    const int quad = lane >> 4;
    const int R    = wave * 16;          // this wave's private 16-row band

    const float2* s2 = (const float2*)s;
    const float2 z2 = make_float2(0.f, 0.f);

    // ---- weight B-fragments straight from global into registers.
    // Layout per lane (c16,quad), frag (g,t,ks): col n = t*16+c16 of gate g
    // (row r = g*50+n of W[150][64]); elements = k = ks*32+quad*8 .. +7.
    // k<50 -> w_hh[r][k]; k=50,51 -> w_ih[r][0..1] (r/z only); k=52 -> fused
    // bias (b_hh, + b_ih for r/z); k>52 -> 0. n>=50 -> all 0.
    bf16x8 wf[3][4][2];
    #pragma unroll
    for (int g = 0; g < 3; ++g) {
        #pragma unroll
        for (int t = 0; t < 4; ++t) {
            int n = t * 16 + c16;
            bool okn = (n < 50);
            int r = g * 50 + n;
            const float* wr = w_hh + r * 50;    // 8B-aligned (200B row stride)
            float2 q0 = okn ? *(const float2*)(wr + quad * 8 + 0) : z2;
            float2 q1 = okn ? *(const float2*)(wr + quad * 8 + 2) : z2;
            float2 q2 = okn ? *(const float2*)(wr + quad * 8 + 4) : z2;
            float2 q3 = okn ? *(const float2*)(wr + quad * 8 + 6) : z2;
            wf[g][t][0] = pack8(q0, q1, q2, q3);

            float2 p0 = z2, p1 = z2, p2 = z2, p3 = z2;
            if (okn) {
                if (quad < 2) {                  // k = 32..47: all w_hh
                    int kb = 32 + quad * 8;
                    p0 = *(const float2*)(wr + kb + 0);
                    p1 = *(const float2*)(wr + kb + 2);
                    p2 = *(const float2*)(wr + kb + 4);
                    p3 = *(const float2*)(wr + kb + 6);
                } else if (quad == 2) {          // k = 48..55: boundary patch
                    p0 = *(const float2*)(wr + 48);
                    float wx0 = (g < 2) ? w_ih[r * 2 + 0] : 0.f;
                    float wx1 = (g < 2) ? w_ih[r * 2 + 1] : 0.f;
                    p1 = make_float2(wx0, wx1);
                    float bb = b_hh[r] + ((g < 2) ? b_ih[r] : 0.f);
                    p2 = make_float2(bb, 0.f);
                }                                // quad 3 (k 56..63): zeros
            }
            wf[g][t][1] = pack8(p0, p1, p2, p3);
        }
    }

    // ---- hoisted per-lane constants (loop-invariant global reads) ----
    float wi0[4], wi1[4], bi[4], aw0[4], aw1[4], awc[4];
    #pragma unroll
    for (int t = 0; t < 4; ++t) {
        int j = t * 16 + c16;
        bool ok = (j < 50);
        wi0[t] = ok ? w_ih[(100 + j) * 2 + 0] : 0.f;
        wi1[t] = ok ? w_ih[(100 + j) * 2 + 1] : 0.f;
        bi[t]  = ok ? b_ih[100 + j]           : 0.f;
        aw0[t] = ok ? actor_w[j]              : 0.f;
        aw1[t] = ok ? actor_w[50 + j]         : 0.f;
        awc[t] = ok ? critic_w[j]             : 0.f;
    }
    const float ab0 = actor_b[0], ab1 = actor_b[1], cb = critic_b[0];

    float* oc = out + (long long)Btot * 50;
    float2* opi = (float2*)(out + (long long)Btot * 51);

    int bt = blockIdx.x;
    while (bt < nTiles) {
        const int rowbase = bt * 64;

        // ---- A-fragment loads: lane's row = rowbase+R+c16, 8 consecutive
        // floats per quad. All independent VMEM, issued up front. ----
        const float* hrow = h + (rowbase + R + c16) * 50;
        float2 a00 = *(const float2*)(hrow + quad * 8 + 0);
        float2 a01 = *(const float2*)(hrow + quad * 8 + 2);
        float2 a02 = *(const float2*)(hrow + quad * 8 + 4);
        float2 a03 = *(const float2*)(hrow + quad * 8 + 6);
        float2 b0 = z2, b1 = z2, b2 = z2, b3 = z2;
        if (quad < 2) {                       // k = 32..47
            int kb = 32 + quad * 8;
            b0 = *(const float2*)(hrow + kb + 0);
            b1 = *(const float2*)(hrow + kb + 2);
            b2 = *(const float2*)(hrow + kb + 4);
            b3 = *(const float2*)(hrow + kb + 6);
        } else if (quad == 2) {               // k = 48..55: h48,h49,s0,s1,1,0
            b0 = *(const float2*)(hrow + 48);
            b1 = s2[rowbase + R + c16];
            b2 = make_float2(1.f, 0.f);
        }                                      // quad 3: zeros

        // ---- hv: h_old[row=R+quad*4+reg][j=t*16+c16] direct from global
        // (L1/L2-hot: same rows the A-loads touch). t=3 guarded (OOB). ----
        float hv[4][4];
        float2 srow[4];
        #pragma unroll
        for (int reg = 0; reg < 4; ++reg) {
            const float* hr2 = h + (rowbase + R + quad * 4 + reg) * 50;
            #pragma unroll
            for (int t = 0; t < 4; ++t) {
                int j = t * 16 + c16;
                hv[reg][t] = (j < 50) ? hr2[j] : 0.f;
            }
            srow[reg] = s2[rowbase + R + quad * 4 + reg];
        }

        bf16x8 a0 = pack8(a00, a01, a02, a03);   // k 0..31
        bf16x8 a1 = pack8(b0, b1, b2, b3);       // k 32..63

        float* ob = out + (long long)rowbase * 50;   // 32-bit lane offsets

        // ---- per-t: 6 reg-MFMAs then gate math ----
        float hn_r[4][4];
        #pragma unroll
        for (int t = 0; t < 4; ++t) {
            f32x4 ar = {0.f,0.f,0.f,0.f}, az = ar, an = ar;
            ar = __builtin_amdgcn_mfma_f32_16x16x32_bf16(a0, wf[0][t][0], ar, 0, 0, 0);
            ar = __builtin_amdgcn_mfma_f32_16x16x32_bf16(a1, wf[0][t][1], ar, 0, 0, 0);
            az = __builtin_amdgcn_mfma_f32_16x16x32_bf16(a0, wf[1][t][0], az, 0, 0, 0);
            az = __builtin_amdgcn_mfma_f32_16x16x32_bf16(a1, wf[1][t][1], az, 0, 0, 0);
            an = __builtin_amdgcn_mfma_f32_16x16x32_bf16(a0, wf[2][t][0], an, 0, 0, 0);
            an = __builtin_amdgcn_mfma_f32_16x16x32_bf16(a1, wf[2][t][1], an, 0, 0, 0);

            int j = t * 16 + c16;
            #pragma unroll
            for (int reg = 0; reg < 4; ++reg) {
                int lr = R + quad * 4 + reg;       // C/D: row = quad*4+reg
                float inn = fmaf(srow[reg].y, wi1[t],
                            fmaf(srow[reg].x, wi0[t], bi[t]));
                float rg = __builtin_amdgcn_rcpf(1.f + __expf(-ar[reg]));
                float zg = __builtin_amdgcn_rcpf(1.f + __expf(-az[reg]));
                float x = inn + rg * an[reg];
                float e2 = __expf(2.f * x);   // saturates: ng -> +-1, no NaN
                float ng = 1.f - 2.f * __builtin_amdgcn_rcpf(e2 + 1.f);
                float hnew = fmaf(zg, hv[reg][t] - ng, ng);
                hn_r[reg][t] = (j < 50) ? hnew : 0.f;
                if (j < 50) ob[lr * 50 + j] = hnew;
            }
        }

        // ---- heads from registers: DPP row_ror rotate-reduce (VALU pipe) ----
        float sum0[4], sum1[4], sumc[4];
        #pragma unroll
        for (int reg = 0; reg < 4; ++reg) {
            float p0 = 0.f, p1 = 0.f, pc = 0.f;
            #pragma unroll
            for (int t = 0; t < 4; ++t) {
                p0 = fmaf(hn_r[reg][t], aw0[t], p0);
                p1 = fmaf(hn_r[reg][t], aw1[t], p1);
                pc = fmaf(hn_r[reg][t], awc[t], pc);
            }
            sum0[reg] = row16_sum(p0);
            sum1[reg] = row16_sum(p1);
            sumc[reg] = row16_sum(pc);
        }
        if (c16 < 4) {   // lane c16==reg writes row quad*4+c16
            float A0 = (c16 == 0) ? sum0[0] : (c16 == 1) ? sum0[1]
                     : (c16 == 2) ? sum0[2] : sum0[3];
            float A1 = (c16 == 0) ? sum1[0] : (c16 == 1) ? sum1[1]
                     : (c16 == 2) ? sum1[2] : sum1[3];
            float C  = (c16 == 0) ? sumc[0] : (c16 == 1) ? sumc[1]
                     : (c16 == 2) ? sumc[2] : sumc[3];
            int gr = rowbase + R + quad * 4 + c16;
            oc[gr] = C + cb;
            A0 += ab0; A1 += ab1;
            float m = fmaxf(A0, A1);
            float e0 = __expf(A0 - m), e1 = __expf(A1 - m);
            float inv = 1.f / (e0 + e1);
            float2 pv; pv.x = e0 * inv; pv.y = e1 * inv;
            opi[gr] = pv;
        }
        bt += gridDim.x;
    }
}

extern "C" void kernel_launch(void* const* d_in, const int* in_sizes, int n_in,
                              void* d_out, int out_size, void* d_ws, size_t ws_size,
                              hipStream_t stream) {
    const float* s        = (const float*)d_in[0];
    const float* h        = (const float*)d_in[1];
    const float* w_ih     = (const float*)d_in[2];
    const float* w_hh     = (const float*)d_in[3];
    const float* b_ih     = (const float*)d_in[4];
    const float* b_hh     = (const float*)d_in[5];
    const float* actor_w  = (const float*)d_in[6];
    const float* actor_b  = (const float*)d_in[7];
    const float* critic_w = (const float*)d_in[8];
    const float* critic_b = (const float*)d_in[9];
    float* out = (float*)d_out;

    int Btot = in_sizes[1] / 50;          // 262144
    int nTiles = Btot / 64;               // 4096 (exact)
    int grid = nTiles < 1024 ? nTiles : 1024;

    gru_fused<<<grid, BDIM, 0, stream>>>(s, h, w_ih, w_hh, b_ih, b_hh,
                                         actor_w, actor_b, critic_w, critic_b,
                                         out, Btot, nTiles);
}

// Round 9
// 149.608 us; speedup vs baseline: 1.0297x; 1.0297x over previous
//
#include <hip/hip_runtime.h>
#include <hip/hip_bf16.h>

// GRUCell (B=262144, IN=2, H=50) + critic + actor-softmax.
// Inputs fp32, outputs fp32: d_out = h_new[B,50] | c[B,1] | pi[B,2].
// Extended-K MFMA: x[64]=[h(50),s(2),1,0...], W[64]=[w_hh,w_ih,bias,0...].
// R14 (resubmit; previous round failed on container acquisition, never
// ran): R11's "prefetch both tiles" (VGPR=56) and R12's "hoist weights to
// regs" (VGPR=108 < the 96 needed for fragments alone) were both silently
// DEFEATED by the compiler -- the experiments never ran. R13 proved LDS
// x-staging beats direct-global (72us vs 51us). R14 enforces the weight
// hoist for real:
//  - K1 (pack_w, 1536 thr, ~1-2us): f2bf-swizzles all 24 weight fragments
//    into d_ws in the exact per-lane layout.
//  - K2: each lane loads its 24 fragments via 24 coalesced dwordx4 reads
//    from ws (L2-broadcast), PINNED in registers with asm volatile so the
//    allocator cannot sink/re-read them (no LDS copy exists to remat).
//  - wlds deleted -> LDS = 9216B (xlds only); const zone init is per-wave
//    -> NO __syncthreads anywhere; t-loop is pure reg-MFMA.
//  - x-staging / hv-from-LDS / DPP heads / prefetch pipeline: as R7/R10.
// Discriminators: VGPR >= 180 (hoist happened), LDS_Block_Size 9216,
// bank conflicts drop; FETCH ~27MB = no spills.

#define BDIM 256

typedef __bf16 bf16x8 __attribute__((ext_vector_type(8)));
typedef float f32x4 __attribute__((ext_vector_type(4)));
typedef unsigned u32x4 __attribute__((ext_vector_type(4)));
typedef unsigned __attribute__((may_alias)) u32a;
typedef unsigned short __attribute__((may_alias)) u16a;

__device__ __forceinline__ float bf2f(unsigned short u) {
    union { unsigned u; float f; } x; x.u = ((unsigned)u) << 16; return x.f;
}
__device__ __forceinline__ unsigned short f2bf(float f) {   // pack kernel only
    union { float f; unsigned u; } x; x.f = f;
    unsigned r = x.u + 0x7fffu + ((x.u >> 16) & 1u);
    return (unsigned short)(r >> 16);
}
__device__ __forceinline__ unsigned packbf(float a, float b) {  // v_cvt_pk_bf16_f32
    union { __hip_bfloat162 h; unsigned u; } c;
    c.h = __float22bfloat162_rn(make_float2(a, b));
    return c.u;
}
__device__ __forceinline__ bf16x8 ldsfrag(const unsigned short* p) {
    bf16x8 v; __builtin_memcpy(&v, p, 16); return v;   // alias-safe b128 read
}

// DPP rotate-add within each 16-lane row: VALU pipe, no LDS.
template <int CTRL>
__device__ __forceinline__ float dpp_add(float v) {
    int s = __builtin_bit_cast(int, v);
    int r = __builtin_amdgcn_update_dpp(s, s, CTRL, 0xf, 0xf, false);
    return v + __builtin_bit_cast(float, r);
}
__device__ __forceinline__ float row16_sum(float v) {
    v = dpp_add<0x128>(v);   // + ror 8
    v = dpp_add<0x124>(v);   // + ror 4
    v = dpp_add<0x122>(v);   // + ror 2
    v = dpp_add<0x121>(v);   // + ror 1 -> every lane has full 16-lane sum
    return v;
}

// ---- K1: pack weight fragments into ws (exact old-wlds layout).
// e = (g<<9)|(t<<7)|(ks<<6)|lane ; ws[e] = 16B (8 bf16, k ascending).
__global__ __launch_bounds__(256, 1) void pack_w(
    const float* __restrict__ w_ih, const float* __restrict__ w_hh,
    const float* __restrict__ b_ih, const float* __restrict__ b_hh,
    u32x4* __restrict__ ws)
{
    int e = blockIdx.x * 256 + threadIdx.x;
    if (e >= 1536) return;
    int ln = e & 63;
    int ks = (e >> 6) & 1;
    int t  = (e >> 7) & 3;
    int g  = e >> 9;
    int n  = t * 16 + (ln & 15);
    int kbase = ks * 32 + (ln >> 4) * 8;
    unsigned short vals[8];
    if (n < 50) {
        int r = g * 50 + n;
        #pragma unroll
        for (int i = 0; i < 8; ++i) {
            int k = kbase + i;
            float v = 0.f;
            if (k < 50)       v = w_hh[r * 50 + k];
            else if (k == 50) v = (g < 2) ? w_ih[r * 2 + 0] : 0.f;
            else if (k == 51) v = (g < 2) ? w_ih[r * 2 + 1] : 0.f;
            else if (k == 52) {
                v = b_hh[r];                 // n-gate: b_hh only
                if (g < 2) v += b_ih[r];     // r/z: both biases fused
            }
            vals[i] = f2bf(v);
        }
    } else {
        #pragma unroll
        for (int i = 0; i < 8; ++i) vals[i] = 0;
    }
    u32x4 o;
    #pragma unroll
    for (int i = 0; i < 4; ++i)
        o[i] = (unsigned)vals[2 * i] | ((unsigned)vals[2 * i + 1] << 16);
    ws[e] = o;
}

__global__ __launch_bounds__(BDIM, 2) void gru_fused(
    const float* __restrict__ s,
    const float* __restrict__ h,
    const float* __restrict__ w_ih,
    const float* __restrict__ actor_w,
    const float* __restrict__ actor_b,
    const float* __restrict__ critic_w,
    const float* __restrict__ critic_b,
    const float* __restrict__ b_ih,
    const u32x4* __restrict__ ws,
    float* __restrict__ out,
    int Btot, int nTiles)
{
    // bf16 x-tile: 64 rows x 72 shorts (144B stride); shorts 0..49 h, 50..51 s,
    // 52 = 1.0, 53..63 = 0, 64..71 pad. Per-wave band -> no barrier needed.
    __shared__ __align__(16) unsigned short xlds[64 * 72];

    const int tid  = threadIdx.x;
    const int wave = tid >> 6;           // 0..3
    const int lane = tid & 63;
    const int c16  = lane & 15;
    const int quad = lane >> 4;
    const int R    = wave * 16;          // this wave's private 16-row band

    u32a* xlds32 = (u32a*)xlds;

    // ---- per-wave const-zone init of OWN band (rows R..R+15, dwords 26..35):
    // short 52 = 1.0 bf16, 53..71 = 0. Written once, read only by this wave.
    for (int i = lane; i < 160; i += 64) {
        int row = R + i / 10, dk = 26 + i % 10;
        xlds32[row * 36 + dk] = (i % 10 == 0) ? 0x00003f80u : 0u;
    }
    asm volatile("" ::: "memory");

    // ---- weight fragments: 24 coalesced dwordx4 loads from ws, pinned in
    // registers (no LDS copy exists -> allocator must keep them). ----
    bf16x8 wf[3][4][2];
    #pragma unroll
    for (int g = 0; g < 3; ++g)
        #pragma unroll
        for (int t = 0; t < 4; ++t)
            #pragma unroll
            for (int ks = 0; ks < 2; ++ks) {
                u32x4 w = ws[(g << 9) + (t << 7) + (ks << 6) + lane];
                asm volatile("" :: "v"(w));   // pin: forbid sinking/re-read
                wf[g][t][ks] = __builtin_bit_cast(bf16x8, w);
            }

    // ---- hoisted per-lane constants (loop-invariant global reads) ----
    float wi0[4], wi1[4], bi[4], aw0[4], aw1[4], awc[4];
    #pragma unroll
    for (int t = 0; t < 4; ++t) {
        int j = t * 16 + c16;
        bool ok = (j < 50);
        wi0[t] = ok ? w_ih[(100 + j) * 2 + 0] : 0.f;
        wi1[t] = ok ? w_ih[(100 + j) * 2 + 1] : 0.f;
        bi[t]  = ok ? b_ih[100 + j]           : 0.f;
        aw0[t] = ok ? actor_w[j]              : 0.f;
        aw1[t] = ok ? actor_w[50 + j]         : 0.f;
        awc[t] = ok ? critic_w[j]             : 0.f;
    }
    const float ab0 = actor_b[0], ab1 = actor_b[1], cb = critic_b[0];

    const float2* h2 = (const float2*)h;
    const float2* s2 = (const float2*)s;
    float* oc = out + (long long)Btot * 50;
    float2* opi = (float2*)(out + (long long)Btot * 51);

    // ---- prefetch first tile (this wave's 16 rows: 400 h-float2 + 16 s) ----
    float2 pf[7];
    int bt = blockIdx.x;
    {
        long long hb = (long long)(bt * 64 + R) * 25;
        #pragma unroll
        for (int j = 0; j < 6; ++j) pf[j] = h2[hb + lane + j * 64];
        if (lane < 16)      pf[6] = h2[hb + 384 + lane];
        else if (lane < 32) pf[6] = s2[bt * 64 + R + lane - 16];
    }

    while (bt < nTiles) {
        const int rowbase = bt * 64;

        // ---- stage own band: regs -> LDS (alias-safe u32a writes) ----
        #pragma unroll
        for (int j = 0; j < 6; ++j) {
            int d = lane + j * 64;
            int r = d / 25, dk = d - r * 25;
            xlds32[(R + r) * 36 + dk] = packbf(pf[j].x, pf[j].y);
        }
        if (lane < 16)
            xlds32[(R + 15) * 36 + 9 + lane] = packbf(pf[6].x, pf[6].y);
        else if (lane < 32)
            xlds32[(R + lane - 16) * 36 + 25] = packbf(pf[6].x, pf[6].y);

        // compiler fence: staging writes ordered before all following reads
        asm volatile("" ::: "memory");

        // ---- issue next tile's loads (latency hidden by compute) ----
        const int nbt = bt + gridDim.x;
        {
            int pb = (nbt < nTiles) ? nbt : bt;
            long long hb = (long long)(pb * 64 + R) * 25;
            #pragma unroll
            for (int j = 0; j < 6; ++j) pf[j] = h2[hb + lane + j * 64];
            if (lane < 16)      pf[6] = h2[hb + 384 + lane];
            else if (lane < 32) pf[6] = s2[pb * 64 + R + lane - 16];
        }

        // ---- s rows for gate math (L2-hot, 16-lane broadcast) ----
        float2 srow[4];
        #pragma unroll
        for (int reg = 0; reg < 4; ++reg)
            srow[reg] = s2[rowbase + R + quad * 4 + reg];

        // ---- A fragments (own band, alias-safe reads) ----
        const unsigned short* arow = &xlds[(R + c16) * 72 + quad * 8];
        bf16x8 a0 = ldsfrag(arow);        // k 0..31
        bf16x8 a1 = ldsfrag(arow + 32);   // k 32..63

        float* ob = out + (long long)rowbase * 50;   // 32-bit lane offsets

        // ---- per-t: 6 reg-MFMAs then gate math ----
        float hn_r[4][4];
        #pragma unroll
        for (int t = 0; t < 4; ++t) {
            f32x4 ar = {0.f,0.f,0.f,0.f}, az = ar, an = ar;
            ar = __builtin_amdgcn_mfma_f32_16x16x32_bf16(a0, wf[0][t][0], ar, 0, 0, 0);
            ar = __builtin_amdgcn_mfma_f32_16x16x32_bf16(a1, wf[0][t][1], ar, 0, 0, 0);
            az = __builtin_amdgcn_mfma_f32_16x16x32_bf16(a0, wf[1][t][0], az, 0, 0, 0);
            az = __builtin_amdgcn_mfma_f32_16x16x32_bf16(a1, wf[1][t][1], az, 0, 0, 0);
            an = __builtin_amdgcn_mfma_f32_16x16x32_bf16(a0, wf[2][t][0], an, 0, 0, 0);
            an = __builtin_amdgcn_mfma_f32_16x16x32_bf16(a1, wf[2][t][1], an, 0, 0, 0);

            int j = t * 16 + c16;
            #pragma unroll
            for (int reg = 0; reg < 4; ++reg) {
                int lr = R + quad * 4 + reg;       // C/D: row = quad*4+reg
                float inn = fmaf(srow[reg].y, wi1[t],
                            fmaf(srow[reg].x, wi0[t], bi[t]));
                float rg = __builtin_amdgcn_rcpf(1.f + __expf(-ar[reg]));
                float zg = __builtin_amdgcn_rcpf(1.f + __expf(-az[reg]));
                float x = inn + rg * an[reg];
                float e2 = __expf(2.f * x);   // saturates: ng -> +-1, no NaN
                float ng = 1.f - 2.f * __builtin_amdgcn_rcpf(e2 + 1.f);
                float hv = bf2f(((const u16a*)xlds)[lr * 72 + j]);
                float hnew = fmaf(zg, hv - ng, ng);
                hn_r[reg][t] = (j < 50) ? hnew : 0.f;
                if (j < 50) ob[lr * 50 + j] = hnew;
            }
        }

        // ---- heads from registers: DPP row_ror rotate-reduce (VALU pipe) ----
        float sum0[4], sum1[4], sumc[4];
        #pragma unroll
        for (int reg = 0; reg < 4; ++reg) {
            float p0 = 0.f, p1 = 0.f, pc = 0.f;
            #pragma unroll
            for (int t = 0; t < 4; ++t) {
                p0 = fmaf(hn_r[reg][t], aw0[t], p0);
                p1 = fmaf(hn_r[reg][t], aw1[t], p1);
                pc = fmaf(hn_r[reg][t], awc[t], pc);
            }
            sum0[reg] = row16_sum(p0);
            sum1[reg] = row16_sum(p1);
            sumc[reg] = row16_sum(pc);
        }
        if (c16 < 4) {   // lane c16==reg writes row quad*4+c16
            float A0 = (c16 == 0) ? sum0[0] : (c16 == 1) ? sum0[1]
                     : (c16 == 2) ? sum0[2] : sum0[3];
            float A1 = (c16 == 0) ? sum1[0] : (c16 == 1) ? sum1[1]
                     : (c16 == 2) ? sum1[2] : sum1[3];
            float C  = (c16 == 0) ? sumc[0] : (c16 == 1) ? sumc[1]
                     : (c16 == 2) ? sumc[2] : sumc[3];
            int gr = rowbase + R + quad * 4 + c16;
            oc[gr] = C + cb;
            A0 += ab0; A1 += ab1;
            float m = fmaxf(A0, A1);
            float e0 = __expf(A0 - m), e1 = __expf(A1 - m);
            float inv = 1.f / (e0 + e1);
            float2 pv; pv.x = e0 * inv; pv.y = e1 * inv;
            opi[gr] = pv;
        }
        bt = nbt;
    }
}

extern "C" void kernel_launch(void* const* d_in, const int* in_sizes, int n_in,
                              void* d_out, int out_size, void* d_ws, size_t ws_size,
                              hipStream_t stream) {
    const float* s        = (const float*)d_in[0];
    const float* h        = (const float*)d_in[1];
    const float* w_ih     = (const float*)d_in[2];
    const float* w_hh     = (const float*)d_in[3];
    const float* b_ih     = (const float*)d_in[4];
    const float* b_hh     = (const float*)d_in[5];
    const float* actor_w  = (const float*)d_in[6];
    const float* actor_b  = (const float*)d_in[7];
    const float* critic_w = (const float*)d_in[8];
    const float* critic_b = (const float*)d_in[9];
    float* out = (float*)d_out;

    int Btot = in_sizes[1] / 50;          // 262144
    int nTiles = Btot / 64;               // 4096 (exact)
    int grid = nTiles < 1024 ? nTiles : 1024;

    u32x4* ws = (u32x4*)d_ws;             // needs 1536*16 = 24576 B

    pack_w<<<6, 256, 0, stream>>>(w_ih, w_hh, b_ih, b_hh, ws);
    gru_fused<<<grid, BDIM, 0, stream>>>(s, h, w_ih, actor_w, actor_b,
                                         critic_w, critic_b, b_ih,
                                         (const u32x4*)ws, out, Btot, nTiles);
}

// Round 10
// 139.388 us; speedup vs baseline: 1.1052x; 1.0733x over previous
//
#include <hip/hip_runtime.h>
#include <hip/hip_bf16.h>

// GRUCell (B=262144, IN=2, H=50) + critic + actor-softmax.
// Inputs fp32, outputs fp32: d_out = h_new[B,50] | c[B,1] | pi[B,2].
// Extended-K MFMA: x[64]=[h(50),s(2),1,0...], W[64]=[w_hh,w_ih,bias,0...].
// R15: the invariant across R7-R14 is EFFECTIVE HBM BW ~1.7 TB/s:
// time = bytes/BW in every round (48us = 83MB/1.7TB/s; R13 72us =
// 83/1.15; R8 116us = 376/3.2). The chip does 6.3 TB/s; we sustain 1.7
// because in-flight bytes/CU ~1KB (7x8B loads per wave, idle 75% of each
// tile) vs the ~6KB Little's-law requirement. R15 restructures for MLP:
//  - ONE 128-row tile per block, 8 waves, NO loop: all 56 h/s loads of a
//    block issue at inst 0; grid 2048 -> ~8 blocks/CU refill so starting
//    blocks' loads overlap resident blocks' compute (~26KB reads in
//    flight per starting block).
//  - wlds init = coalesced 24.5KB copy from R14's pack_w workspace (the
//    scattered per-element weight prologue is gone).
//  - LDS 18432(xlds,128 rows)+24576(wlds)=43008 -> 3 blocks/CU -> 24
//    waves/CU cap (75%), VGPR ~60-76 under (512,4) cap 128.
//  - per-wave body: IDENTICAL to the known-good R7/R10/R11 code (16-row
//    band, LDS x-staging, wlds-from-LDS MFMA, DPP heads, VALU trims).
// Discriminators: hbm_gbps >= 2.5 TB/s and dur ~25-35us if MLP theory
// right; flat 48us despite occupancy rise = theory dead (roofline
// evidence). Spill tripwire: FETCH ~27MB, WRITE ~54MB.

#define BDIM 512

typedef __bf16 bf16x8 __attribute__((ext_vector_type(8)));
typedef float f32x4 __attribute__((ext_vector_type(4)));
typedef unsigned u32x4 __attribute__((ext_vector_type(4)));
typedef unsigned __attribute__((may_alias)) u32a;
typedef unsigned short __attribute__((may_alias)) u16a;

__device__ __forceinline__ float bf2f(unsigned short u) {
    union { unsigned u; float f; } x; x.u = ((unsigned)u) << 16; return x.f;
}
__device__ __forceinline__ unsigned short f2bf(float f) {   // pack kernel only
    union { float f; unsigned u; } x; x.f = f;
    unsigned r = x.u + 0x7fffu + ((x.u >> 16) & 1u);
    return (unsigned short)(r >> 16);
}
__device__ __forceinline__ unsigned packbf(float a, float b) {  // v_cvt_pk_bf16_f32
    union { __hip_bfloat162 h; unsigned u; } c;
    c.h = __float22bfloat162_rn(make_float2(a, b));
    return c.u;
}
__device__ __forceinline__ bf16x8 ldsfrag(const unsigned short* p) {
    bf16x8 v; __builtin_memcpy(&v, p, 16); return v;   // alias-safe b128 read
}

// DPP rotate-add within each 16-lane row: VALU pipe, no LDS.
template <int CTRL>
__device__ __forceinline__ float dpp_add(float v) {
    int s = __builtin_bit_cast(int, v);
    int r = __builtin_amdgcn_update_dpp(s, s, CTRL, 0xf, 0xf, false);
    return v + __builtin_bit_cast(float, r);
}
__device__ __forceinline__ float row16_sum(float v) {
    v = dpp_add<0x128>(v);   // + ror 8
    v = dpp_add<0x124>(v);   // + ror 4
    v = dpp_add<0x122>(v);   // + ror 2
    v = dpp_add<0x121>(v);   // + ror 1 -> every lane has full 16-lane sum
    return v;
}

// ---- K1: pack weight fragments into ws (exact wlds layout).
// e = (g<<9)|(t<<7)|(ks<<6)|lane ; ws[e] = 16B (8 bf16, k ascending).
__global__ __launch_bounds__(256, 1) void pack_w(
    const float* __restrict__ w_ih, const float* __restrict__ w_hh,
    const float* __restrict__ b_ih, const float* __restrict__ b_hh,
    u32x4* __restrict__ ws)
{
    int e = blockIdx.x * 256 + threadIdx.x;
    if (e >= 1536) return;
    int ln = e & 63;
    int ks = (e >> 6) & 1;
    int t  = (e >> 7) & 3;
    int g  = e >> 9;
    int n  = t * 16 + (ln & 15);
    int kbase = ks * 32 + (ln >> 4) * 8;
    unsigned short vals[8];
    if (n < 50) {
        int r = g * 50 + n;
        #pragma unroll
        for (int i = 0; i < 8; ++i) {
            int k = kbase + i;
            float v = 0.f;
            if (k < 50)       v = w_hh[r * 50 + k];
            else if (k == 50) v = (g < 2) ? w_ih[r * 2 + 0] : 0.f;
            else if (k == 51) v = (g < 2) ? w_ih[r * 2 + 1] : 0.f;
            else if (k == 52) {
                v = b_hh[r];                 // n-gate: b_hh only
                if (g < 2) v += b_ih[r];     // r/z: both biases fused
            }
            vals[i] = f2bf(v);
        }
    } else {
        #pragma unroll
        for (int i = 0; i < 8; ++i) vals[i] = 0;
    }
    u32x4 o;
    #pragma unroll
    for (int i = 0; i < 4; ++i)
        o[i] = (unsigned)vals[2 * i] | ((unsigned)vals[2 * i + 1] << 16);
    ws[e] = o;
}

__global__ __launch_bounds__(BDIM, 4) void gru_fused(
    const float* __restrict__ s,
    const float* __restrict__ h,
    const float* __restrict__ w_ih,
    const float* __restrict__ actor_w,
    const float* __restrict__ actor_b,
    const float* __restrict__ critic_w,
    const float* __restrict__ critic_b,
    const float* __restrict__ b_ih,
    const u32x4* __restrict__ ws,
    float* __restrict__ out,
    int Btot, int nTiles)
{
    // bf16 x-tile: 128 rows x 72 shorts (144B stride); shorts 0..49 h,
    // 50..51 s, 52 = 1.0, 53..63 = 0, 64..71 pad.
    __shared__ __align__(16) unsigned short xlds[128 * 72];   // 18432 B
    // weight B-fragments: [g(3)][t(4)][ks(2)][lane(64)][8 bf16]
    __shared__ __align__(16) unsigned short wlds[1536 * 8];   // 24576 B

    const int tid  = threadIdx.x;
    const int wave = tid >> 6;           // 0..7
    const int lane = tid & 63;
    const int c16  = lane & 15;
    const int quad = lane >> 4;
    const int R    = wave * 16;          // this wave's private 16-row band

    u32a* xlds32 = (u32a*)xlds;

    const int bt = blockIdx.x;
    const int rowbase = bt * 128;
    const float2* h2 = (const float2*)h;
    const float2* s2 = (const float2*)s;

    // ---- FIRST: issue this wave's h/s loads (the block's 25.6KB of reads
    // all go in flight at block start; init below hides the latency) ----
    float2 pf[7];
    {
        long long hb = (long long)(rowbase + R) * 25;
        #pragma unroll
        for (int j = 0; j < 6; ++j) pf[j] = h2[hb + lane + j * 64];
        if (lane < 16)      pf[6] = h2[hb + 384 + lane];
        else if (lane < 32) pf[6] = s2[rowbase + R + lane - 16];
    }

    // ---- init: wlds = coalesced 16B copy from prepacked ws (L2-hot) ----
    u32x4* wlds16 = (u32x4*)wlds;
    for (int i = tid; i < 1536; i += BDIM)
        wlds16[i] = ws[i];

    // ---- init: const zone of OWN band (rows R..R+15, dwords 26..35):
    // short 52 = 1.0 bf16, 53..71 = 0. ----
    for (int i = lane; i < 160; i += 64) {
        int row = R + i / 10, dk = 26 + i % 10;
        xlds32[row * 36 + dk] = (i % 10 == 0) ? 0x00003f80u : 0u;
    }

    // ---- hoisted per-lane constants (loop-invariant global reads) ----
    float wi0[4], wi1[4], bi[4], aw0[4], aw1[4], awc[4];
    #pragma unroll
    for (int t = 0; t < 4; ++t) {
        int j = t * 16 + c16;
        bool ok = (j < 50);
        wi0[t] = ok ? w_ih[(100 + j) * 2 + 0] : 0.f;
        wi1[t] = ok ? w_ih[(100 + j) * 2 + 1] : 0.f;
        bi[t]  = ok ? b_ih[100 + j]           : 0.f;
        aw0[t] = ok ? actor_w[j]              : 0.f;
        aw1[t] = ok ? actor_w[50 + j]         : 0.f;
        awc[t] = ok ? critic_w[j]             : 0.f;
    }
    const float ab0 = actor_b[0], ab1 = actor_b[1], cb = critic_b[0];

    __syncthreads();   // wlds visible to all waves

    // ---- stage own band: regs -> LDS (alias-safe u32a writes) ----
    #pragma unroll
    for (int j = 0; j < 6; ++j) {
        int d = lane + j * 64;
        int r = d / 25, dk = d - r * 25;
        xlds32[(R + r) * 36 + dk] = packbf(pf[j].x, pf[j].y);
    }
    if (lane < 16)
        xlds32[(R + 15) * 36 + 9 + lane] = packbf(pf[6].x, pf[6].y);
    else if (lane < 32)
        xlds32[(R + lane - 16) * 36 + 25] = packbf(pf[6].x, pf[6].y);

    // compiler fence: staging writes ordered before all following reads
    asm volatile("" ::: "memory");

    // ---- s rows for gate math (L2-hot, 16-lane broadcast) ----
    float2 srow[4];
    #pragma unroll
    for (int reg = 0; reg < 4; ++reg)
        srow[reg] = s2[rowbase + R + quad * 4 + reg];

    // ---- A fragments (own band, alias-safe reads) ----
    const unsigned short* arow = &xlds[(R + c16) * 72 + quad * 8];
    bf16x8 a0 = ldsfrag(arow);        // k 0..31
    bf16x8 a1 = ldsfrag(arow + 32);   // k 32..63

    float* ob = out + (long long)rowbase * 50;   // 32-bit lane offsets
    float* oc = out + (long long)Btot * 50;
    float2* opi = (float2*)(out + (long long)Btot * 51);

    // ---- per-t: 6 MFMAs then gate math ----
    float hn_r[4][4];
    #pragma unroll
    for (int t = 0; t < 4; ++t) {
        f32x4 ar = {0.f,0.f,0.f,0.f}, az = ar, an = ar;
        const int tb = (t * 128 + lane) * 8;   // shorts; ks +512, g +4096
        bf16x8 br0 = ldsfrag(&wlds[tb]);
        bf16x8 br1 = ldsfrag(&wlds[tb + 512]);
        bf16x8 bz0 = ldsfrag(&wlds[tb + 4096]);
        bf16x8 bz1 = ldsfrag(&wlds[tb + 4608]);
        bf16x8 bn0 = ldsfrag(&wlds[tb + 8192]);
        bf16x8 bn1 = ldsfrag(&wlds[tb + 8704]);
        ar = __builtin_amdgcn_mfma_f32_16x16x32_bf16(a0, br0, ar, 0, 0, 0);
        ar = __builtin_amdgcn_mfma_f32_16x16x32_bf16(a1, br1, ar, 0, 0, 0);
        az = __builtin_amdgcn_mfma_f32_16x16x32_bf16(a0, bz0, az, 0, 0, 0);
        az = __builtin_amdgcn_mfma_f32_16x16x32_bf16(a1, bz1, az, 0, 0, 0);
        an = __builtin_amdgcn_mfma_f32_16x16x32_bf16(a0, bn0, an, 0, 0, 0);
        an = __builtin_amdgcn_mfma_f32_16x16x32_bf16(a1, bn1, an, 0, 0, 0);

        int j = t * 16 + c16;
        #pragma unroll
        for (int reg = 0; reg < 4; ++reg) {
            int lr = R + quad * 4 + reg;       // C/D: row = quad*4+reg
            float inn = fmaf(srow[reg].y, wi1[t],
                        fmaf(srow[reg].x, wi0[t], bi[t]));
            float rg = __builtin_amdgcn_rcpf(1.f + __expf(-ar[reg]));
            float zg = __builtin_amdgcn_rcpf(1.f + __expf(-az[reg]));
            float x = inn + rg * an[reg];
            float e2 = __expf(2.f * x);   // saturates: ng -> +-1, no NaN
            float ng = 1.f - 2.f * __builtin_amdgcn_rcpf(e2 + 1.f);
            float hv = bf2f(((const u16a*)xlds)[lr * 72 + j]);
            float hnew = fmaf(zg, hv - ng, ng);
            hn_r[reg][t] = (j < 50) ? hnew : 0.f;
            if (j < 50) ob[lr * 50 + j] = hnew;
        }
    }

    // ---- heads from registers: DPP row_ror rotate-reduce (VALU pipe) ----
    float sum0[4], sum1[4], sumc[4];
    #pragma unroll
    for (int reg = 0; reg < 4; ++reg) {
        float p0 = 0.f, p1 = 0.f, pc = 0.f;
        #pragma unroll
        for (int t = 0; t < 4; ++t) {
            p0 = fmaf(hn_r[reg][t], aw0[t], p0);
            p1 = fmaf(hn_r[reg][t], aw1[t], p1);
            pc = fmaf(hn_r[reg][t], awc[t], pc);
        }
        sum0[reg] = row16_sum(p0);
        sum1[reg] = row16_sum(p1);
        sumc[reg] = row16_sum(pc);
    }
    if (c16 < 4) {   // lane c16==reg writes row quad*4+c16
        float A0 = (c16 == 0) ? sum0[0] : (c16 == 1) ? sum0[1]
                 : (c16 == 2) ? sum0[2] : sum0[3];
        float A1 = (c16 == 0) ? sum1[0] : (c16 == 1) ? sum1[1]
                 : (c16 == 2) ? sum1[2] : sum1[3];
        float C  = (c16 == 0) ? sumc[0] : (c16 == 1) ? sumc[1]
                 : (c16 == 2) ? sumc[2] : sumc[3];
        int gr = rowbase + R + quad * 4 + c16;
        oc[gr] = C + cb;
        A0 += ab0; A1 += ab1;
        float m = fmaxf(A0, A1);
        float e0 = __expf(A0 - m), e1 = __expf(A1 - m);
        float inv = 1.f / (e0 + e1);
        float2 pv; pv.x = e0 * inv; pv.y = e1 * inv;
        opi[gr] = pv;
    }
}

extern "C" void kernel_launch(void* const* d_in, const int* in_sizes, int n_in,
                              void* d_out, int out_size, void* d_ws, size_t ws_size,
                              hipStream_t stream) {
    const float* s        = (const float*)d_in[0];
    const float* h        = (const float*)d_in[1];
    const float* w_ih     = (const float*)d_in[2];
    const float* w_hh     = (const float*)d_in[3];
    const float* b_ih     = (const float*)d_in[4];
    const float* b_hh     = (const float*)d_in[5];
    const float* actor_w  = (const float*)d_in[6];
    const float* actor_b  = (const float*)d_in[7];
    const float* critic_w = (const float*)d_in[8];
    const float* critic_b = (const float*)d_in[9];
    float* out = (float*)d_out;

    int Btot = in_sizes[1] / 50;          // 262144
    int nTiles = Btot / 128;              // 2048 (exact)

    u32x4* ws = (u32x4*)d_ws;             // needs 1536*16 = 24576 B

    pack_w<<<6, 256, 0, stream>>>(w_ih, w_hh, b_ih, b_hh, ws);
    gru_fused<<<nTiles, BDIM, 0, stream>>>(s, h, w_ih, actor_w, actor_b,
                                           critic_w, critic_b, b_ih,
                                           (const u32x4*)ws, out, Btot, nTiles);
}